// Round 9
// baseline (955.524 us; speedup 1.0000x reference)
//
#include <hip/hip_runtime.h>
#include <hip/hip_bf16.h>
#include <math.h>

#define C_IN   32
#define D0     64
#define H0     96
#define W0     192
#define DD     193
#define HH     288
#define WW     576
#define NPIX   (HH*WW)            // 165888
#define NPIX4  (NPIX/4)           // 41472
#define NVOL   ((size_t)DD*NPIX)  // 32,016,384
#define NCOST  (D0*H0*W0)         // 1,179,648
#define NCOST4 (NCOST/4)          // 294912

// ---------------- LDS-tiled conv3d, channel-split x4
#define CZC   8
#define CSL   (CZC + 2)        // 10 slices (z-halo)
#define CROWS 6
#define CSTR  72               // padded row stride (words)

__global__ __launch_bounds__(256)
void conv3d_split_kernel(const float* __restrict__ x,
                         const float* __restrict__ w,
                         float* __restrict__ partial) {
    __shared__ __align__(16) float sb[2][CSL][CROWS][CSTR];
    const int tid = threadIdx.x;
    const int tx = tid & 63, ty = tid >> 6;
    const int wb = blockIdx.x * 64, hb = blockIdx.y * 4;
    const int zc = blockIdx.z & 7, part = blockIdx.z >> 3;
    const int z0 = zc * CZC;
    const int cbase = part * 8;

    float acc[CZC];
    #pragma unroll
    for (int i = 0; i < CZC; ++i) acc[i] = 0.f;

    const float4 f4zero = {0.f, 0.f, 0.f, 0.f};

    #define STAGE(b, ci)                                                          \
    {                                                                             \
        const float* xc = x + (size_t)(ci) * (D0 * H0 * W0);                      \
        _Pragma("unroll")                                                         \
        for (int t0 = 0; t0 < 4; ++t0) {                                          \
            int t = t0 * 256 + tid;                                               \
            if (t < 960) {                                                        \
                int sl = t / 96; int rem = t - sl * 96;                           \
                int r = rem >> 4, v = rem & 15;                                   \
                int zz = z0 - 1 + sl, hh = hb - 1 + r;                            \
                bool ok = (unsigned)zz < (unsigned)D0 && (unsigned)hh < (unsigned)H0; \
                float4 val = ok ? *(const float4*)(xc + ((size_t)zz * H0 + hh) * W0 + wb + 4 * v) \
                                : f4zero;                                         \
                *(float4*)&sb[b][sl][r][4 + 4 * v] = val;                         \
            }                                                                     \
        }                                                                         \
        if (tid < 120) {                                                          \
            int sl = tid / 12; int e = tid - sl * 12;                             \
            int r = e >> 1, side = e & 1;                                         \
            int zz = z0 - 1 + sl, hh = hb - 1 + r;                                \
            int ww = side ? wb + 64 : wb - 1;                                     \
            bool ok = (unsigned)zz < (unsigned)D0 && (unsigned)hh < (unsigned)H0  \
                      && (unsigned)ww < (unsigned)W0;                             \
            sb[b][sl][r][side ? 68 : 3] = ok ? xc[((size_t)zz * H0 + hh) * W0 + ww] : 0.f; \
        }                                                                         \
    }

    STAGE(0, cbase);
    __syncthreads();

    for (int c = 0; c < 8; ++c) {
        const int b = c & 1;
        if (c + 1 < 8) STAGE(b ^ 1, cbase + c + 1);

        const float* wc = w + (cbase + c) * 27;
        float wr[27];
        #pragma unroll
        for (int t = 0; t < 27; ++t) wr[t] = wc[t];

        #pragma unroll
        for (int sl = 0; sl < CSL; ++sl) {
            float tap[9];
            #pragma unroll
            for (int i = 0; i < 3; ++i)
                #pragma unroll
                for (int j = 0; j < 3; ++j)
                    tap[i * 3 + j] = sb[b][sl][ty + i][tx + 3 + j];
            if (sl < CZC) {
                float cs = 0.f;
                #pragma unroll
                for (int t = 0; t < 9; ++t) cs += wr[t] * tap[t];
                acc[sl] += cs;
            }
            if (sl >= 1 && sl - 1 < CZC) {
                float cs = 0.f;
                #pragma unroll
                for (int t = 0; t < 9; ++t) cs += wr[9 + t] * tap[t];
                acc[sl - 1] += cs;
            }
            if (sl >= 2) {
                float cs = 0.f;
                #pragma unroll
                for (int t = 0; t < 9; ++t) cs += wr[18 + t] * tap[t];
                acc[sl - 2] += cs;
            }
        }
        __syncthreads();
    }
    #undef STAGE

    float* po = partial + (size_t)part * NCOST;
    #pragma unroll
    for (int i = 0; i < CZC; ++i)
        po[((size_t)(z0 + i) * H0 + (hb + ty)) * W0 + (wb + tx)] = acc[i];
}

// ---------------- combine 4 partials -> cost (float4)
__global__ void combine_kernel(const float4* __restrict__ partial, float4* __restrict__ cost) {
    int i = blockIdx.x * 256 + threadIdx.x;
    if (i >= NCOST4) return;
    float4 a = partial[i];
    float4 b = partial[i + NCOST4];
    float4 c = partial[i + 2 * NCOST4];
    float4 d = partial[i + 3 * NCOST4];
    float4 r;
    r.x = a.x + b.x + c.x + d.x;
    r.y = a.y + b.y + c.y + d.y;
    r.z = a.z + b.z + c.z + d.z;
    r.w = a.w + b.w + c.w + d.w;
    cost[i] = r;
}

// ---------------- per-pixel 1/L1-norm over 75 guidance channels (float4)
__global__ void invnorm_kernel(const float4* __restrict__ lg, float4* __restrict__ inv) {
    int p = blockIdx.x * 256 + threadIdx.x;
    if (p >= NPIX4) return;
    float4 s = {0.f, 0.f, 0.f, 0.f};
    for (int c = 0; c < 75; ++c) {
        float4 v = lg[(size_t)c * NPIX4 + p];
        s.x += fabsf(v.x); s.y += fabsf(v.y); s.z += fabsf(v.z); s.w += fabsf(v.w);
    }
    float4 r;
    r.x = 1.0f / fmaxf(s.x, 1e-12f);
    r.y = 1.0f / fmaxf(s.y, 1e-12f);
    r.z = 1.0f / fmaxf(s.z, 1e-12f);
    r.w = 1.0f / fmaxf(s.w, 1e-12f);
    inv[p] = r;
}

// ---------------- trilinear resize cost(64,96,192) -> out(193,288,576)
__global__ void resize_kernel(const float* __restrict__ cost, float* __restrict__ out) {
    size_t idx = (size_t)blockIdx.x * 256 + threadIdx.x;
    if (idx >= NVOL) return;
    int w = (int)(idx % WW);
    int t = (int)(idx / WW);
    int h = t % HH;
    int d = t / HH;

    float sd = fminf(fmaxf((d + 0.5f) * (64.0f / 193.0f) - 0.5f, 0.0f), 63.0f);
    int d0 = (int)floorf(sd); int d1 = min(d0 + 1, 63); float fd = sd - (float)d0;
    float sh = fminf(fmaxf((h + 0.5f) * (96.0f / 288.0f) - 0.5f, 0.0f), 95.0f);
    int h0 = (int)floorf(sh); int h1 = min(h0 + 1, 95); float fh = sh - (float)h0;
    float sw = fminf(fmaxf((w + 0.5f) * (192.0f / 576.0f) - 0.5f, 0.0f), 191.0f);
    int w0 = (int)floorf(sw); int w1 = min(w0 + 1, 191); float fw = sw - (float)w0;

    #define CV(dz, hy, wx) cost[((size_t)(dz) * H0 + (hy)) * W0 + (wx)]
    float v000 = CV(d0, h0, w0), v001 = CV(d0, h0, w1);
    float v010 = CV(d0, h1, w0), v011 = CV(d0, h1, w1);
    float v100 = CV(d1, h0, w0), v101 = CV(d1, h0, w1);
    float v110 = CV(d1, h1, w0), v111 = CV(d1, h1, w1);
    #undef CV
    float a = v000 * (1.f - fw) + v001 * fw;
    float b = v010 * (1.f - fw) + v011 * fw;
    float c = v100 * (1.f - fw) + v101 * fw;
    float e = v110 * (1.f - fw) + v111 * fw;
    float lo = a * (1.f - fh) + b * fh;
    float hi = c * (1.f - fh) + e * fh;
    out[idx] = lo * (1.f - fd) + hi * fd;
}

// ---------------- LDS-tiled LGA pass, d-split x3, async-STAGE + raw barrier
// Per slice: ds_write(e) -> issue loads(e+1) -> [lgkmcnt(0); s_barrier] -> compute(e).
// The raw barrier (vs __syncthreads) does NOT drain vmcnt, so the prefetch
// loads and the output store stay in flight across the barrier; the compiler
// waits on them only at next round's ds_write, a full compute phase later.
// Double-buffered LDS keeps the single barrier per round race-free.
// MODE 0: plain store. MODE 1: store exp(-v), atomic per-pixel sum into accS.
// MODE 2: no store; accumulate A=sum v*d, S=sum |v|, atomics into accA/accS.
#define TW 64
#define TH 8
#define HWT 68
#define HHT 12
#define NCELL (HWT*HHT)   // 816
#define NTHR 512
#define DCHUNK 65
#define NDCH  3           // ceil(193/65)

template<int MODE>
__global__ __launch_bounds__(NTHR, 2)
void lga_tiled_kernel(const float* __restrict__ in, float* __restrict__ out,
                      const float* __restrict__ g, const float* __restrict__ inv,
                      const float* __restrict__ inscale,
                      float* __restrict__ accAbuf, float* __restrict__ accSbuf) {
    __shared__ float sbuf[2][NCELL];
    const int tid = threadIdx.x;
    const int tx = tid & 63, ty = tid >> 6;
    const int wb = blockIdx.x * TW, hb = blockIdx.y * TH;
    const int pix = (hb + ty) * WW + (wb + tx);
    const int ds = blockIdx.z * DCHUNK;
    const int de = min(ds + DCHUNK, DD);
    const int e0 = max(ds - 1, 0);
    const int emax = min(de, DD - 1);

    const int c0 = tid, c1 = tid + NTHR;
    const bool has1 = (c1 < NCELL);
    int r0 = c0 / HWT, q0 = c0 - r0 * HWT;
    int hh0 = hb - 2 + r0, ww0 = wb - 2 + q0;
    const bool v0 = (unsigned)hh0 < (unsigned)HH && (unsigned)ww0 < (unsigned)WW;
    const size_t off0 = v0 ? (size_t)hh0 * WW + ww0 : 0;
    const float is0 = (inscale != nullptr && v0) ? inscale[off0] : 1.0f;
    int r1 = c1 / HWT, q1 = c1 - r1 * HWT;
    int hh1 = hb - 2 + r1, ww1 = wb - 2 + q1;
    const bool v1 = has1 && (unsigned)hh1 < (unsigned)HH && (unsigned)ww1 < (unsigned)WW;
    const size_t off1 = v1 ? (size_t)hh1 * WW + ww1 : 0;
    const float is1 = (inscale != nullptr && v1) ? inscale[off1] : 1.0f;

    const float s = inv[pix];
    float g0[25], g1[25], g2[25];
    #pragma unroll
    for (int c = 0; c < 25; ++c) g0[c] = g[(size_t)c * NPIX + pix] * s;
    #pragma unroll
    for (int c = 0; c < 25; ++c) g1[c] = g[(size_t)(25 + c) * NPIX + pix] * s;
    #pragma unroll
    for (int c = 0; c < 25; ++c) g2[c] = g[(size_t)(50 + c) * NPIX + pix] * s;

    // prologue: load slice e0 into registers
    float sa, sb2;
    {
        const float* sl = in + (size_t)e0 * NPIX;
        sa  = v0 ? sl[off0] * is0 : 0.0f;
        sb2 = v1 ? sl[off1] * is1 : 0.0f;
    }

    float accA = 0.f, accB = 0.f;
    float aloc = 0.f, sloc = 0.f;

    #define EMIT(n, val)                                                          \
    {                                                                             \
        if constexpr (MODE == 0) {                                                \
            out[(size_t)(n) * NPIX + pix] = (val);                                \
        } else if constexpr (MODE == 1) {                                         \
            float ev = __expf(-(val));                                            \
            out[(size_t)(n) * NPIX + pix] = ev;                                   \
            sloc += ev;                                                           \
        } else {                                                                  \
            aloc += (val) * (float)(n);                                           \
            sloc += fabsf(val);                                                   \
        }                                                                         \
    }

    for (int e = e0; e <= emax; ++e) {
        // 1. commit slice e to LDS (vmcnt waits only for these two loads' regs)
        float* wp = sbuf[e & 1];
        wp[c0] = sa;
        if (has1) wp[c1] = sb2;
        // 2. issue loads for slice e+1 (stay in flight across the barrier)
        if (e < emax) {
            const float* nsl = in + (size_t)(e + 1) * NPIX;
            sa  = v0 ? nsl[off0] * is0 : 0.0f;
            sb2 = v1 ? nsl[off1] * is1 : 0.0f;
        }
        // 3. LDS-only drain + raw barrier (no vmcnt drain, unlike __syncthreads)
        asm volatile("s_waitcnt lgkmcnt(0)" ::: "memory");
        __builtin_amdgcn_s_barrier();
        // 4. compute slice e
        const float* cur = sbuf[e & 1];
        float cc0 = 0.f, cc1 = 0.f, cc2 = 0.f;
        #pragma unroll
        for (int i = 0; i < 5; ++i) {
            const float* row = cur + (ty + i) * HWT + tx;
            #pragma unroll
            for (int j = 0; j < 5; ++j) {
                float v = row[j];
                cc0 += g0[i * 5 + j] * v;
                cc1 += g1[i * 5 + j] * v;
                cc2 += g2[i * 5 + j] * v;
            }
        }
        int n = e - 1;
        if (n >= ds && n < de) {
            float rr = accA + cc2;
            EMIT(n, rr);
        }
        accA = accB + cc1;
        accB = cc0;
    }
    if (de == DD) {
        EMIT(DD - 1, accA);  // slice DD is zero-pad: no c2 term
    }
    #undef EMIT

    if constexpr (MODE == 1) {
        atomicAdd(&accSbuf[pix], sloc);
    } else if constexpr (MODE == 2) {
        atomicAdd(&accAbuf[pix], aloc);
        atomicAdd(&accSbuf[pix], sloc);
    }
}

// ---------------- reciprocal in place (float4)
__global__ void rcp_kernel(float4* __restrict__ v) {
    int p = blockIdx.x * 256 + threadIdx.x;
    if (p >= NPIX4) return;
    float4 a = v[p];
    a.x = 1.0f / a.x; a.y = 1.0f / a.y; a.z = 1.0f / a.z; a.w = 1.0f / a.w;
    v[p] = a;
}

// ---------------- finish: out = A / max(S, eps) (float4)
__global__ void finish_kernel(const float4* __restrict__ A, const float4* __restrict__ S,
                              float4* __restrict__ out) {
    int p = blockIdx.x * 256 + threadIdx.x;
    if (p >= NPIX4) return;
    float4 a = A[p], s = S[p];
    float4 r;
    r.x = a.x / fmaxf(s.x, 1e-12f);
    r.y = a.y / fmaxf(s.y, 1e-12f);
    r.z = a.z / fmaxf(s.z, 1e-12f);
    r.w = a.w / fmaxf(s.w, 1e-12f);
    out[p] = r;
}

extern "C" void kernel_launch(void* const* d_in, const int* in_sizes, int n_in,
                              void* d_out, int out_size, void* d_ws, size_t ws_size,
                              hipStream_t stream) {
    const float* x    = (const float*)d_in[0];
    const float* lg1  = (const float*)d_in[1];
    const float* lg2  = (const float*)d_in[2];
    const float* cw   = (const float*)d_in[3];
    float* out = (float*)d_out;

    float* ws   = (float*)d_ws;
    float* buf0 = ws;
    float* buf1 = buf0 + NVOL;
    float* cost = buf1 + NVOL;
    float* inv1 = cost + NCOST;
    float* inv2 = inv1 + NPIX;
    float* rden = inv2 + NPIX;
    float* Abuf = rden + NPIX;
    float* Sbuf = Abuf + NPIX;
    float* partials = buf1;  // dead before lga#1 writes buf1

    const dim3 lgrid(WW / TW, HH / TH, NDCH);

    // 0. zero the atomic accumulators
    hipMemsetAsync(rden, 0, NPIX * sizeof(float), stream);
    hipMemsetAsync(Abuf, 0, NPIX * sizeof(float), stream);
    hipMemsetAsync(Sbuf, 0, NPIX * sizeof(float), stream);

    // 1. conv3d (channel-split x4) + combine
    conv3d_split_kernel<<<dim3(W0 / 64, H0 / 4, (D0 / CZC) * 4), 256, 0, stream>>>(x, cw, partials);
    combine_kernel<<<(NCOST4 + 255) / 256, 256, 0, stream>>>((const float4*)partials, (float4*)cost);
    // 2. guidance inverse L1 norms
    invnorm_kernel<<<(NPIX4 + 255) / 256, 256, 0, stream>>>((const float4*)lg1, (float4*)inv1);
    invnorm_kernel<<<(NPIX4 + 255) / 256, 256, 0, stream>>>((const float4*)lg2, (float4*)inv2);
    // 3. trilinear upsample
    resize_kernel<<<(int)((NVOL + 255) / 256), 256, 0, stream>>>(cost, buf0);
    // 4. LGA passes (d-split x3). #2 fuses softmax exp+denominator; #4 fuses final reduce.
    lga_tiled_kernel<0><<<lgrid, NTHR, 0, stream>>>(buf0, buf1, lg1, inv1, nullptr, nullptr, nullptr);
    lga_tiled_kernel<1><<<lgrid, NTHR, 0, stream>>>(buf1, buf0, lg1, inv1, nullptr, nullptr, rden);
    rcp_kernel<<<(NPIX4 + 255) / 256, 256, 0, stream>>>((float4*)rden);
    lga_tiled_kernel<0><<<lgrid, NTHR, 0, stream>>>(buf0, buf1, lg2, inv2, rden, nullptr, nullptr);
    lga_tiled_kernel<2><<<lgrid, NTHR, 0, stream>>>(buf1, nullptr, lg2, inv2, nullptr, Abuf, Sbuf);
    // 5. finish: normalize + expectation
    finish_kernel<<<(NPIX4 + 255) / 256, 256, 0, stream>>>((const float4*)Abuf, (const float4*)Sbuf, (float4*)out);
}

// Round 10
// 896.204 us; speedup vs baseline: 1.0662x; 1.0662x over previous
//
#include <hip/hip_runtime.h>
#include <hip/hip_bf16.h>
#include <math.h>

#define C_IN   32
#define D0     64
#define H0     96
#define W0     192
#define DD     193
#define HH     288
#define WW     576
#define NPIX   (HH*WW)            // 165888
#define NPIX4  (NPIX/4)           // 41472
#define NVOL   ((size_t)DD*NPIX)  // 32,016,384
#define NCOST  (D0*H0*W0)         // 1,179,648
#define NCOST4 (NCOST/4)          // 294912

__device__ __forceinline__ float2 f2(float x, float y) { float2 r; r.x = x; r.y = y; return r; }

// ---------------- LDS-tiled conv3d, channel-split x4
#define CZC   8
#define CSL   (CZC + 2)        // 10 slices (z-halo)
#define CROWS 6
#define CSTR  72               // padded row stride (words)

__global__ __launch_bounds__(256)
void conv3d_split_kernel(const float* __restrict__ x,
                         const float* __restrict__ w,
                         float* __restrict__ partial) {
    __shared__ __align__(16) float sb[2][CSL][CROWS][CSTR];
    const int tid = threadIdx.x;
    const int tx = tid & 63, ty = tid >> 6;
    const int wb = blockIdx.x * 64, hb = blockIdx.y * 4;
    const int zc = blockIdx.z & 7, part = blockIdx.z >> 3;
    const int z0 = zc * CZC;
    const int cbase = part * 8;

    float acc[CZC];
    #pragma unroll
    for (int i = 0; i < CZC; ++i) acc[i] = 0.f;

    const float4 f4zero = {0.f, 0.f, 0.f, 0.f};

    #define STAGE(b, ci)                                                          \
    {                                                                             \
        const float* xc = x + (size_t)(ci) * (D0 * H0 * W0);                      \
        _Pragma("unroll")                                                         \
        for (int t0 = 0; t0 < 4; ++t0) {                                          \
            int t = t0 * 256 + tid;                                               \
            if (t < 960) {                                                        \
                int sl = t / 96; int rem = t - sl * 96;                           \
                int r = rem >> 4, v = rem & 15;                                   \
                int zz = z0 - 1 + sl, hh = hb - 1 + r;                            \
                bool ok = (unsigned)zz < (unsigned)D0 && (unsigned)hh < (unsigned)H0; \
                float4 val = ok ? *(const float4*)(xc + ((size_t)zz * H0 + hh) * W0 + wb + 4 * v) \
                                : f4zero;                                         \
                *(float4*)&sb[b][sl][r][4 + 4 * v] = val;                         \
            }                                                                     \
        }                                                                         \
        if (tid < 120) {                                                          \
            int sl = tid / 12; int e = tid - sl * 12;                             \
            int r = e >> 1, side = e & 1;                                         \
            int zz = z0 - 1 + sl, hh = hb - 1 + r;                                \
            int ww = side ? wb + 64 : wb - 1;                                     \
            bool ok = (unsigned)zz < (unsigned)D0 && (unsigned)hh < (unsigned)H0  \
                      && (unsigned)ww < (unsigned)W0;                             \
            sb[b][sl][r][side ? 68 : 3] = ok ? xc[((size_t)zz * H0 + hh) * W0 + ww] : 0.f; \
        }                                                                         \
    }

    STAGE(0, cbase);
    __syncthreads();

    for (int c = 0; c < 8; ++c) {
        const int b = c & 1;
        if (c + 1 < 8) STAGE(b ^ 1, cbase + c + 1);

        const float* wc = w + (cbase + c) * 27;
        float wr[27];
        #pragma unroll
        for (int t = 0; t < 27; ++t) wr[t] = wc[t];

        #pragma unroll
        for (int sl = 0; sl < CSL; ++sl) {
            float tap[9];
            #pragma unroll
            for (int i = 0; i < 3; ++i)
                #pragma unroll
                for (int j = 0; j < 3; ++j)
                    tap[i * 3 + j] = sb[b][sl][ty + i][tx + 3 + j];
            if (sl < CZC) {
                float cs = 0.f;
                #pragma unroll
                for (int t = 0; t < 9; ++t) cs += wr[t] * tap[t];
                acc[sl] += cs;
            }
            if (sl >= 1 && sl - 1 < CZC) {
                float cs = 0.f;
                #pragma unroll
                for (int t = 0; t < 9; ++t) cs += wr[9 + t] * tap[t];
                acc[sl - 1] += cs;
            }
            if (sl >= 2) {
                float cs = 0.f;
                #pragma unroll
                for (int t = 0; t < 9; ++t) cs += wr[18 + t] * tap[t];
                acc[sl - 2] += cs;
            }
        }
        __syncthreads();
    }
    #undef STAGE

    float* po = partial + (size_t)part * NCOST;
    #pragma unroll
    for (int i = 0; i < CZC; ++i)
        po[((size_t)(z0 + i) * H0 + (hb + ty)) * W0 + (wb + tx)] = acc[i];
}

// ---------------- combine 4 partials -> cost (float4)
__global__ void combine_kernel(const float4* __restrict__ partial, float4* __restrict__ cost) {
    int i = blockIdx.x * 256 + threadIdx.x;
    if (i >= NCOST4) return;
    float4 a = partial[i];
    float4 b = partial[i + NCOST4];
    float4 c = partial[i + 2 * NCOST4];
    float4 d = partial[i + 3 * NCOST4];
    float4 r;
    r.x = a.x + b.x + c.x + d.x;
    r.y = a.y + b.y + c.y + d.y;
    r.z = a.z + b.z + c.z + d.z;
    r.w = a.w + b.w + c.w + d.w;
    cost[i] = r;
}

// ---------------- per-pixel 1/L1-norm over 75 guidance channels (float4)
__global__ void invnorm_kernel(const float4* __restrict__ lg, float4* __restrict__ inv) {
    int p = blockIdx.x * 256 + threadIdx.x;
    if (p >= NPIX4) return;
    float4 s = {0.f, 0.f, 0.f, 0.f};
    for (int c = 0; c < 75; ++c) {
        float4 v = lg[(size_t)c * NPIX4 + p];
        s.x += fabsf(v.x); s.y += fabsf(v.y); s.z += fabsf(v.z); s.w += fabsf(v.w);
    }
    float4 r;
    r.x = 1.0f / fmaxf(s.x, 1e-12f);
    r.y = 1.0f / fmaxf(s.y, 1e-12f);
    r.z = 1.0f / fmaxf(s.z, 1e-12f);
    r.w = 1.0f / fmaxf(s.w, 1e-12f);
    inv[p] = r;
}

// ---------------- trilinear resize cost(64,96,192) -> out(193,288,576)
__global__ void resize_kernel(const float* __restrict__ cost, float* __restrict__ out) {
    size_t idx = (size_t)blockIdx.x * 256 + threadIdx.x;
    if (idx >= NVOL) return;
    int w = (int)(idx % WW);
    int t = (int)(idx / WW);
    int h = t % HH;
    int d = t / HH;

    float sd = fminf(fmaxf((d + 0.5f) * (64.0f / 193.0f) - 0.5f, 0.0f), 63.0f);
    int d0 = (int)floorf(sd); int d1 = min(d0 + 1, 63); float fd = sd - (float)d0;
    float sh = fminf(fmaxf((h + 0.5f) * (96.0f / 288.0f) - 0.5f, 0.0f), 95.0f);
    int h0 = (int)floorf(sh); int h1 = min(h0 + 1, 95); float fh = sh - (float)h0;
    float sw = fminf(fmaxf((w + 0.5f) * (192.0f / 576.0f) - 0.5f, 0.0f), 191.0f);
    int w0 = (int)floorf(sw); int w1 = min(w0 + 1, 191); float fw = sw - (float)w0;

    #define CV(dz, hy, wx) cost[((size_t)(dz) * H0 + (hy)) * W0 + (wx)]
    float v000 = CV(d0, h0, w0), v001 = CV(d0, h0, w1);
    float v010 = CV(d0, h1, w0), v011 = CV(d0, h1, w1);
    float v100 = CV(d1, h0, w0), v101 = CV(d1, h0, w1);
    float v110 = CV(d1, h1, w0), v111 = CV(d1, h1, w1);
    #undef CV
    float a = v000 * (1.f - fw) + v001 * fw;
    float b = v010 * (1.f - fw) + v011 * fw;
    float c = v100 * (1.f - fw) + v101 * fw;
    float e = v110 * (1.f - fw) + v111 * fw;
    float lo = a * (1.f - fh) + b * fh;
    float hi = c * (1.f - fh) + e * fh;
    out[idx] = lo * (1.f - fd) + hi * fd;
}

// ---------------- LDS-tiled LGA pass, 2 pixels/thread, wide LDS reads
// 256 threads = 32(x, 2px each) x 8(y). Per slice per thread: stage one float4
// (or edge scalar) into LDS, then 5 rows x 3 float2 reads feed 150 FMAs.
// LDS tile: 12 rows x stride 72; col c <-> global pixel wb + c - 4.
// MODE 0: plain store. MODE 1: store exp(-v), atomic per-pixel sum into accS.
// MODE 2: no store; accumulate A=sum v*d, S=sum |v|, atomics into accA/accS.
#define TW 64
#define TH 8
#define LROWS 12
#define LSTR  72
#define NTHR 256
#define DCHUNK 65
#define NDCH  3           // ceil(193/65)

template<int MODE>
__global__ __launch_bounds__(NTHR, 2)
void lga_tiled_kernel(const float* __restrict__ in, float* __restrict__ out,
                      const float* __restrict__ g, const float* __restrict__ inv,
                      const float* __restrict__ inscale,
                      float* __restrict__ accAbuf, float* __restrict__ accSbuf) {
    __shared__ __align__(16) float sbuf[2][LROWS * LSTR];
    const int tid = threadIdx.x;
    const int tx = tid & 31, ty = tid >> 5;
    const int wb = blockIdx.x * TW, hb = blockIdx.y * TH;
    const int pix0 = (hb + ty) * WW + (wb + 2 * tx);
    const int ds = blockIdx.z * DCHUNK;
    const int de = min(ds + DCHUNK, DD);
    const int e0 = max(ds - 1, 0);
    const int emax = min(de, DD - 1);

    // --- staging task (<=1 per thread): 192 float4 interior + 48 edge scalars
    const bool isVec  = (tid < 192);
    const bool isEdge = (tid >= 192 && tid < 240);
    int vdst = 0; size_t vgoff = 0; bool vok = false;
    int edst = 0; size_t egoff = 0; bool eok = false;
    float4 is4 = {1.f, 1.f, 1.f, 1.f};
    float ise = 1.f;
    if (isVec) {
        int r = tid >> 4, v = tid & 15;
        int hh = hb - 2 + r;
        vok = (unsigned)hh < (unsigned)HH;
        vgoff = vok ? (size_t)hh * WW + wb + 4 * v : 0;
        vdst = r * LSTR + 4 + 4 * v;
        if (inscale != nullptr && vok) is4 = *(const float4*)&inscale[vgoff];
    } else if (isEdge) {
        int t = tid - 192;
        int r = t >> 2, s = t & 3;
        int hh = hb - 2 + r;
        int gc = wb + (s == 0 ? -2 : s == 1 ? -1 : s == 2 ? 64 : 65);
        eok = (unsigned)hh < (unsigned)HH && (unsigned)gc < (unsigned)WW;
        egoff = eok ? (size_t)hh * WW + gc : 0;
        edst = r * LSTR + (s == 0 ? 2 : s == 1 ? 3 : s == 2 ? 68 : 69);
        if (inscale != nullptr && eok) ise = inscale[egoff];
    }

    // --- normalized guidance weights for both pixels (float2 x 75)
    const float2 s2 = *(const float2*)&inv[pix0];
    float2 g0[25], g1[25], g2[25];
    #pragma unroll
    for (int c = 0; c < 25; ++c) {
        float2 v = *(const float2*)&g[(size_t)c * NPIX + pix0];
        g0[c] = f2(v.x * s2.x, v.y * s2.y);
    }
    #pragma unroll
    for (int c = 0; c < 25; ++c) {
        float2 v = *(const float2*)&g[(size_t)(25 + c) * NPIX + pix0];
        g1[c] = f2(v.x * s2.x, v.y * s2.y);
    }
    #pragma unroll
    for (int c = 0; c < 25; ++c) {
        float2 v = *(const float2*)&g[(size_t)(50 + c) * NPIX + pix0];
        g2[c] = f2(v.x * s2.x, v.y * s2.y);
    }

    // prologue: load slice e0 into regs
    float4 va = {0.f, 0.f, 0.f, 0.f};
    float ea = 0.f;
    {
        const float* sl = in + (size_t)e0 * NPIX;
        if (isVec && vok) {
            float4 t = *(const float4*)&sl[vgoff];
            va = make_float4(t.x * is4.x, t.y * is4.y, t.z * is4.z, t.w * is4.w);
        } else if (isEdge && eok) {
            ea = sl[egoff] * ise;
        }
    }

    float2 accA = f2(0.f, 0.f), accB = f2(0.f, 0.f);
    float2 aloc = f2(0.f, 0.f), sloc = f2(0.f, 0.f);

    #define EMIT(n, val)                                                          \
    {                                                                             \
        if constexpr (MODE == 0) {                                                \
            *(float2*)&out[(size_t)(n) * NPIX + pix0] = (val);                    \
        } else if constexpr (MODE == 1) {                                         \
            float2 ev = f2(__expf(-(val).x), __expf(-(val).y));                   \
            *(float2*)&out[(size_t)(n) * NPIX + pix0] = ev;                       \
            sloc.x += ev.x; sloc.y += ev.y;                                       \
        } else {                                                                  \
            aloc.x += (val).x * (float)(n); aloc.y += (val).y * (float)(n);       \
            sloc.x += fabsf((val).x); sloc.y += fabsf((val).y);                   \
        }                                                                         \
    }

    for (int e = e0; e <= emax; ++e) {
        // 1. commit slice e to LDS
        float* wp = sbuf[e & 1];
        if (isVec) {
            *(float4*)&wp[vdst] = va;
        } else if (isEdge) {
            wp[edst] = ea;
        }
        // 2. issue loads for slice e+1 (stay in flight across the barrier)
        if (e < emax) {
            const float* nsl = in + (size_t)(e + 1) * NPIX;
            if (isVec) {
                if (vok) {
                    float4 t = *(const float4*)&nsl[vgoff];
                    va = make_float4(t.x * is4.x, t.y * is4.y, t.z * is4.z, t.w * is4.w);
                }
            } else if (isEdge && eok) {
                ea = nsl[egoff] * ise;
            }
        }
        // 3. LDS drain + raw barrier (no vmcnt drain)
        asm volatile("s_waitcnt lgkmcnt(0)" ::: "memory");
        __builtin_amdgcn_s_barrier();
        // 4. compute slice e: 5 rows x 6-float window -> 2 pixels x 3 convs
        const float* base = sbuf[e & 1] + ty * LSTR + 2 * tx + 2;
        float2 cc0 = f2(0.f, 0.f), cc1 = f2(0.f, 0.f), cc2 = f2(0.f, 0.f);
        #pragma unroll
        for (int i = 0; i < 5; ++i) {
            const float* rp = base + i * LSTR;
            float2 wA = *(const float2*)(rp);
            float2 wB = *(const float2*)(rp + 2);
            float2 wC = *(const float2*)(rp + 4);
            float wl[6] = {wA.x, wA.y, wB.x, wB.y, wC.x, wC.y};
            #pragma unroll
            for (int j = 0; j < 5; ++j) {
                float2 gg;
                gg = g0[i * 5 + j]; cc0.x += gg.x * wl[j]; cc0.y += gg.y * wl[j + 1];
                gg = g1[i * 5 + j]; cc1.x += gg.x * wl[j]; cc1.y += gg.y * wl[j + 1];
                gg = g2[i * 5 + j]; cc2.x += gg.x * wl[j]; cc2.y += gg.y * wl[j + 1];
            }
        }
        int n = e - 1;
        if (n >= ds && n < de) {
            float2 rr = f2(accA.x + cc2.x, accA.y + cc2.y);
            EMIT(n, rr);
        }
        accA = f2(accB.x + cc1.x, accB.y + cc1.y);
        accB = cc0;
    }
    if (de == DD) {
        EMIT(DD - 1, accA);  // slice DD is zero-pad: no c2 term
    }
    #undef EMIT

    if constexpr (MODE == 1) {
        atomicAdd(&accSbuf[pix0], sloc.x);
        atomicAdd(&accSbuf[pix0 + 1], sloc.y);
    } else if constexpr (MODE == 2) {
        atomicAdd(&accAbuf[pix0], aloc.x);
        atomicAdd(&accAbuf[pix0 + 1], aloc.y);
        atomicAdd(&accSbuf[pix0], sloc.x);
        atomicAdd(&accSbuf[pix0 + 1], sloc.y);
    }
}

// ---------------- reciprocal in place (float4)
__global__ void rcp_kernel(float4* __restrict__ v) {
    int p = blockIdx.x * 256 + threadIdx.x;
    if (p >= NPIX4) return;
    float4 a = v[p];
    a.x = 1.0f / a.x; a.y = 1.0f / a.y; a.z = 1.0f / a.z; a.w = 1.0f / a.w;
    v[p] = a;
}

// ---------------- finish: out = A / max(S, eps) (float4)
__global__ void finish_kernel(const float4* __restrict__ A, const float4* __restrict__ S,
                              float4* __restrict__ out) {
    int p = blockIdx.x * 256 + threadIdx.x;
    if (p >= NPIX4) return;
    float4 a = A[p], s = S[p];
    float4 r;
    r.x = a.x / fmaxf(s.x, 1e-12f);
    r.y = a.y / fmaxf(s.y, 1e-12f);
    r.z = a.z / fmaxf(s.z, 1e-12f);
    r.w = a.w / fmaxf(s.w, 1e-12f);
    out[p] = r;
}

extern "C" void kernel_launch(void* const* d_in, const int* in_sizes, int n_in,
                              void* d_out, int out_size, void* d_ws, size_t ws_size,
                              hipStream_t stream) {
    const float* x    = (const float*)d_in[0];
    const float* lg1  = (const float*)d_in[1];
    const float* lg2  = (const float*)d_in[2];
    const float* cw   = (const float*)d_in[3];
    float* out = (float*)d_out;

    float* ws   = (float*)d_ws;
    float* buf0 = ws;
    float* buf1 = buf0 + NVOL;
    float* cost = buf1 + NVOL;
    float* inv1 = cost + NCOST;
    float* inv2 = inv1 + NPIX;
    float* rden = inv2 + NPIX;
    float* Abuf = rden + NPIX;
    float* Sbuf = Abuf + NPIX;
    float* partials = buf1;  // dead before lga#1 writes buf1

    const dim3 lgrid(WW / TW, HH / TH, NDCH);

    // 0. zero the atomic accumulators
    hipMemsetAsync(rden, 0, NPIX * sizeof(float), stream);
    hipMemsetAsync(Abuf, 0, NPIX * sizeof(float), stream);
    hipMemsetAsync(Sbuf, 0, NPIX * sizeof(float), stream);

    // 1. conv3d (channel-split x4) + combine
    conv3d_split_kernel<<<dim3(W0 / 64, H0 / 4, (D0 / CZC) * 4), 256, 0, stream>>>(x, cw, partials);
    combine_kernel<<<(NCOST4 + 255) / 256, 256, 0, stream>>>((const float4*)partials, (float4*)cost);
    // 2. guidance inverse L1 norms
    invnorm_kernel<<<(NPIX4 + 255) / 256, 256, 0, stream>>>((const float4*)lg1, (float4*)inv1);
    invnorm_kernel<<<(NPIX4 + 255) / 256, 256, 0, stream>>>((const float4*)lg2, (float4*)inv2);
    // 3. trilinear upsample
    resize_kernel<<<(int)((NVOL + 255) / 256), 256, 0, stream>>>(cost, buf0);
    // 4. LGA passes (d-split x3). #2 fuses softmax exp+denominator; #4 fuses final reduce.
    lga_tiled_kernel<0><<<lgrid, NTHR, 0, stream>>>(buf0, buf1, lg1, inv1, nullptr, nullptr, nullptr);
    lga_tiled_kernel<1><<<lgrid, NTHR, 0, stream>>>(buf1, buf0, lg1, inv1, nullptr, nullptr, rden);
    rcp_kernel<<<(NPIX4 + 255) / 256, 256, 0, stream>>>((float4*)rden);
    lga_tiled_kernel<0><<<lgrid, NTHR, 0, stream>>>(buf0, buf1, lg2, inv2, rden, nullptr, nullptr);
    lga_tiled_kernel<2><<<lgrid, NTHR, 0, stream>>>(buf1, nullptr, lg2, inv2, nullptr, Abuf, Sbuf);
    // 5. finish: normalize + expectation
    finish_kernel<<<(NPIX4 + 255) / 256, 256, 0, stream>>>((const float4*)Abuf, (const float4*)Sbuf, (float4*)out);
}